// Round 4
// baseline (170.299 us; speedup 1.0000x reference)
//
#include <hip/hip_runtime.h>
#include <hip/hip_bf16.h>
#include <math.h>

// Problem constants (fixed by the reference)
#define NPTS 50000   // N data points
#define DIM  256     // feature dim (K of the GEMM)
#define BQ   2048    // batch of queries (M of the GEMM)
#define NPAD 50048   // N padded to multiple of 128

#define BK   32
#define CH   64      // n-rows per LDS chunk (32 KB -> 5 blocks/CU)
#define NCH  782     // NPAD/CH
#define NG   96      // n-groups; grid = 16 m-tiles x 96 = 1536 = 6 blocks/CU
                     // (5 resident, LDS-limited). 96%8==0 -> b%8 = g%8: all
                     // 16 m-tiles of a group land on one XCD (L2 reuse).
#define LOG2E 1.4426950408889634f

// ---------- fast-path ws layout (float offsets) ----------
//  acc   [0,      2048)
//  x2h   [2048,   4096)   0.5*log2e*||x||^2
//  t     [4096,  54144)   0.5*log2e*||s||^2 - log2|w|  (+inf when w==0)
//  sgn   [54144, 104192)  label sign
//  xb    [104192, 366336)   bf16 x
//  sb    [366336, 6772480)  bf16 s (NPAD rows, 0-padded)
#define WS_ACC 0
#define WS_X2  2048
#define WS_T   4096
#define WS_SGN 54144
#define WS_XB  104192
#define WS_SB  366336
#define WS_TOTAL_BYTES (6772480ull * 4ull)  // 27,089,920 B

// ---------- v1 fallback ws layout ----------
#define V1_ACC 0
#define V1_X2  2048
#define V1_S2  4096
#define V1_W   54096

typedef __bf16 bf16x8 __attribute__((ext_vector_type(8)));
typedef __bf16 bf16x4 __attribute__((ext_vector_type(4)));
typedef float  f32x4  __attribute__((ext_vector_type(4)));
typedef unsigned int u32;

__device__ __forceinline__ float fast_exp2(float v) {
#if __has_builtin(__builtin_amdgcn_exp2f)
  return __builtin_amdgcn_exp2f(v);   // raw v_exp_f32
#else
  return exp2f(v);
#endif
}

__device__ __forceinline__ void async_copy16(const __bf16* g, __bf16* l) {
  __builtin_amdgcn_global_load_lds(
      (const __attribute__((address_space(1))) u32*)g,
      (__attribute__((address_space(3))) u32*)l, 16, 0, 0);
}

// ============================================================
// FAST PATH (bf16, verified line)
// ============================================================

// One wave per row: fp32->bf16 convert into ws, plus folded epilogue
// constants t = s2h - log2|w| and sign. Blocks 0..7 zero the accumulator.
__global__ __launch_bounds__(256) void svm_precvt9(
    const float* __restrict__ x, const float* __restrict__ s,
    const float* __restrict__ labels, const float* __restrict__ lambdas,
    float* __restrict__ ws) {
  const int wid  = blockIdx.x * 4 + (threadIdx.x >> 6);
  const int lane = threadIdx.x & 63;
  __bf16* xb = (__bf16*)(ws + WS_XB);
  __bf16* sb = (__bf16*)(ws + WS_SB);

  if (blockIdx.x < 8) ws[WS_ACC + blockIdx.x * 256 + threadIdx.x] = 0.0f;

  if (wid < NPAD) {
    float4 v = make_float4(0.f, 0.f, 0.f, 0.f);
    if (wid < NPTS)
      v = reinterpret_cast<const float4*>(s + (size_t)wid * DIM)[lane];
    bf16x4 h = { (__bf16)v.x, (__bf16)v.y, (__bf16)v.z, (__bf16)v.w };
    *reinterpret_cast<bf16x4*>(sb + (size_t)wid * DIM + lane * 4) = h;
    float ss = v.x * v.x + v.y * v.y + v.z * v.z + v.w * v.w;
    #pragma unroll
    for (int off = 32; off > 0; off >>= 1) ss += __shfl_xor(ss, off);
    if (lane == 0) {
      float s2h = 0.5f * LOG2E * ss;
      float lam = (wid < NPTS) ? lambdas[wid] : 0.0f;
      float lab = (wid < NPTS) ? labels[wid] : 1.0f;
      float mag = lam > 0.0f ? lam : 0.0f;
      ws[WS_T + wid]   = (mag > 0.0f) ? s2h - log2f(mag) : __builtin_inff();
      ws[WS_SGN + wid] = lab;
    }
  } else if (wid < NPAD + BQ) {
    int r = wid - NPAD;
    float4 v = reinterpret_cast<const float4*>(x + (size_t)r * DIM)[lane];
    bf16x4 h = { (__bf16)v.x, (__bf16)v.y, (__bf16)v.z, (__bf16)v.w };
    *reinterpret_cast<bf16x4*>(xb + (size_t)r * DIM + lane * 4) = h;
    float ss = v.x * v.x + v.y * v.y + v.z * v.z + v.w * v.w;
    #pragma unroll
    for (int off = 32; off > 0; off >>= 1) ss += __shfl_xor(ss, off);
    if (lane == 0) ws[WS_X2 + r] = 0.5f * LOG2E * ss;
  }
}

// main13: byte-identical per-chunk structure to the verified round-0 kernel
// (single 32 KB buffer, 2-barrier loop, mi=2, afr[2][8]=64 VGPR pinned,
// zero-conflict swizzle). ONE change: grid 768 -> 1536 (NG=96) so 5 blocks
// co-reside per CU (LDS-limited) = 20 waves/CU. Counters said latency-bound
// (MfmaUtil~VALUBusy~30%, occ 26%): inter-block overlap is the missing
// factor — one block's vmcnt-drain hides under the other four's MFMA.
// Honest div/mod-96 mapping (bijective; round-0's &47 was not).
__global__ __launch_bounds__(256, 2) void svm_main13(float* __restrict__ ws) {
  // [kt][n=64][32k] with 16B slot swizzle: slot(n,c) = c ^ ((n>>1)&3)
  __shared__ __bf16 sB[8 * CH * 32];  // 32 KB

  const __bf16* xb = (const __bf16*)(ws + WS_XB);
  const __bf16* sb = (const __bf16*)(ws + WS_SB);
  const float* x2g = ws + WS_X2;
  const float* tg  = ws + WS_T;
  const float* sgg = ws + WS_SGN;
  float* accOut    = ws + WS_ACC;

  const int t    = threadIdx.x;
  const int wave = t >> 6;
  const int lane = t & 63;
  const int quad = lane >> 4;
  const int l16  = lane & 15;
  const int g    = blockIdx.x % NG;   // n-group 0..95 (true mod: bijective)
  const int mt   = blockIdx.x / NG;   // m-tile 0..15
  const int m0   = mt * 128;
  const int c0   = (NCH * g) / NG;
  const int c1   = (NCH * (g + 1)) / NG;

  // A fragments: 2 mi x 8 kt x 16 B = 64 VGPR, loaded once, pinned opaque.
  f32x4 afr[2][8];
  #pragma unroll
  for (int mi = 0; mi < 2; ++mi)
    #pragma unroll
    for (int kt = 0; kt < 8; ++kt)
      afr[mi][kt] = *reinterpret_cast<const f32x4*>(
          xb + (size_t)(m0 + wave * 32 + mi * 16 + l16) * DIM + kt * BK + quad * 8);
  #pragma unroll
  for (int mi = 0; mi < 2; ++mi)
    #pragma unroll
    for (int kt = 0; kt < 8; ++kt)
      asm volatile("" : "+v"(afr[mi][kt]));  // no remat, stays in VGPRs

  float runAcc[2][4] = {{0.f, 0.f, 0.f, 0.f}, {0.f, 0.f, 0.f, 0.f}};

  // staging source swizzle (lane-only): slot fetched = (l&3) ^ ((l>>3)&3)
  const int srcswz = ((lane & 3) ^ ((lane >> 3) & 3)) * 8;  // bf16 elems
  // read-side swizzled 16B slot for this lane's B fragment
  const int rdswz = (quad ^ ((l16 >> 1) & 3)) * 8;          // bf16 elems

  for (int c = c0; c < c1; ++c) {
    __syncthreads();  // prior chunk's LDS reads done

    // Stage 64-n chunk [kt][n][32k], swizzled. 8 instrs/wave, 1 KB each.
    #pragma unroll
    for (int i = 0; i < 8; ++i) {
      int chn = wave * 8 + i;           // 0..31
      int kt = chn >> 2;                // 0..7
      int nb = (chn & 3) * 16;          // 0,16,32,48
      const __bf16* src = sb + (size_t)(c * CH + nb + (lane >> 2)) * DIM
                             + kt * BK + srcswz;
      async_copy16(src, &sB[kt * (CH * 32) + nb * 32] + lane * 8);
    }
    __syncthreads();  // vmcnt drain

    // Epilogue constants issued before MFMA so their latency hides under it.
    float tt[4], sg[4];
    #pragma unroll
    for (int ni = 0; ni < 4; ++ni) {
      int n = c * CH + ni * 16 + l16;
      tt[ni] = tg[n];
      sg[ni] = sgg[n];
    }

    f32x4 acc[2][4];
    #pragma unroll
    for (int mi = 0; mi < 2; ++mi)
      #pragma unroll
      for (int ni = 0; ni < 4; ++ni)
        acc[mi][ni] = (f32x4)(0.0f);

    #pragma unroll
    for (int kt = 0; kt < 8; ++kt) {
      bf16x8 bfv[4];
      #pragma unroll
      for (int ni = 0; ni < 4; ++ni)
        bfv[ni] = *reinterpret_cast<const bf16x8*>(
            &sB[kt * (CH * 32) + (ni * 16 + l16) * 32 + rdswz]);
      #pragma unroll
      for (int mi = 0; mi < 2; ++mi)
        #pragma unroll
        for (int ni = 0; ni < 4; ++ni)
          acc[mi][ni] = __builtin_amdgcn_mfma_f32_16x16x32_bf16(
              __builtin_bit_cast(bf16x8, afr[mi][kt]), bfv[ni],
              acc[mi][ni], 0, 0, 0);
    }

    // Hoisted epilogue: p += sgn * exp2(dot*log2e - t_n); x2 applied at end.
    #pragma unroll
    for (int mi = 0; mi < 2; ++mi)
      #pragma unroll
      for (int reg = 0; reg < 4; ++reg) {
        float p = runAcc[mi][reg];
        #pragma unroll
        for (int ni = 0; ni < 4; ++ni)
          p = __builtin_fmaf(sg[ni],
                fast_exp2(__builtin_fmaf(acc[mi][ni][reg], LOG2E, -tt[ni])), p);
        runAcc[mi][reg] = p;
      }
  }

  // reduce over the 16 n-column lanes; scale by exp2(-x2h); one atomic/row.
  #pragma unroll
  for (int mi = 0; mi < 2; ++mi)
    #pragma unroll
    for (int reg = 0; reg < 4; ++reg) {
      float v = runAcc[mi][reg];
      v += __shfl_xor(v, 1);
      v += __shfl_xor(v, 2);
      v += __shfl_xor(v, 4);
      v += __shfl_xor(v, 8);
      if (l16 == 0) {
        int row = m0 + wave * 32 + mi * 16 + quad * 4 + reg;
        atomicAdd(&accOut[row], fast_exp2(-x2g[row]) * v);
      }
    }
}

// ============================================================
// V1 FALLBACK (used only if ws_size too small)
// ============================================================

__global__ __launch_bounds__(256) void svm_precompute(
    const float* __restrict__ x, const float* __restrict__ s,
    const float* __restrict__ labels, const float* __restrict__ lambdas,
    float* __restrict__ ws) {
  int wid  = blockIdx.x * 4 + (threadIdx.x >> 6);
  int lane = threadIdx.x & 63;
  const float* src;
  if (wid < NPTS)           src = s + (size_t)wid * DIM;
  else if (wid < NPTS + BQ) src = x + (size_t)(wid - NPTS) * DIM;
  else return;
  float4 v = reinterpret_cast<const float4*>(src)[lane];
  float ss = v.x * v.x + v.y * v.y + v.z * v.z + v.w * v.w;
  #pragma unroll
  for (int off = 32; off > 0; off >>= 1) ss += __shfl_xor(ss, off);
  if (lane == 0) {
    if (wid < NPTS) {
      ws[V1_S2 + wid] = ss;
      float lam = lambdas[wid];
      ws[V1_W + wid] = labels[wid] * (lam > 0.0f ? lam : 0.0f);
    } else {
      ws[V1_X2 + (wid - NPTS)] = ss;
    }
  }
}

__global__ __launch_bounds__(256) void svm_main(
    const float* __restrict__ x, const float* __restrict__ s,
    const float* __restrict__ ws) {
  __shared__ __bf16 sA[128 * BK];
  __shared__ __bf16 sB2[128 * BK];

  const int t    = threadIdx.x;
  const int wave = t >> 6;
  const int lane = t & 63;
  const int quad = lane >> 4;
  const int l16  = lane & 15;
  const int wm   = (wave & 1) * 64;
  const int wn   = (wave >> 1) * 64;
  const int bRow0 = blockIdx.y * 128;
  const int n0    = blockIdx.x * 128;

  f32x4 acc[4][4];
  #pragma unroll
  for (int i = 0; i < 4; ++i)
    #pragma unroll
    for (int j = 0; j < 4; ++j)
      acc[i][j] = (f32x4)(0.0f);

  for (int kt = 0; kt < DIM / BK; ++kt) {
    const int k0 = kt * BK;
    __syncthreads();
    #pragma unroll
    for (int i = 0; i < 4; ++i) {
      int slot = t + i * 256;
      int r  = slot >> 3;
      int c4 = slot & 7;
      float4 va = reinterpret_cast<const float4*>(
          x + (size_t)(bRow0 + r) * DIM + k0)[c4];
      bf16x4 ha = { (__bf16)va.x, (__bf16)va.y, (__bf16)va.z, (__bf16)va.w };
      *reinterpret_cast<bf16x4*>(&sA[r * BK + c4 * 4]) = ha;

      int nrow = n0 + r;
      float4 vb = make_float4(0.f, 0.f, 0.f, 0.f);
      if (nrow < NPTS)
        vb = reinterpret_cast<const float4*>(
            s + (size_t)nrow * DIM + k0)[c4];
      bf16x4 hb = { (__bf16)vb.x, (__bf16)vb.y, (__bf16)vb.z, (__bf16)vb.w };
      *reinterpret_cast<bf16x4*>(&sB2[r * BK + c4 * 4]) = hb;
    }
    __syncthreads();

    bf16x8 af[4], bfv[4];
    #pragma unroll
    for (int mi = 0; mi < 4; ++mi)
      af[mi] = *reinterpret_cast<const bf16x8*>(
          &sA[(wm + mi * 16 + l16) * BK + quad * 8]);
    #pragma unroll
    for (int ni = 0; ni < 4; ++ni)
      bfv[ni] = *reinterpret_cast<const bf16x8*>(
          &sB2[(wn + ni * 16 + l16) * BK + quad * 8]);
    #pragma unroll
    for (int mi = 0; mi < 4; ++mi)
      #pragma unroll
      for (int ni = 0; ni < 4; ++ni)
        acc[mi][ni] = __builtin_amdgcn_mfma_f32_16x16x32_bf16(
            af[mi], bfv[ni], acc[mi][ni], 0, 0, 0);
  }

  const float* x2g = ws + V1_X2;
  const float* s2g = ws + V1_S2;
  const float* wg  = ws + V1_W;
  float* accOut    = (float*)ws + V1_ACC;

  float s2v[4], wv[4];
  #pragma unroll
  for (int ni = 0; ni < 4; ++ni) {
    int n = n0 + wn + ni * 16 + l16;
    bool ok = n < NPTS;
    s2v[ni] = ok ? s2g[n] : 0.0f;
    wv[ni]  = ok ? wg[n]  : 0.0f;
  }
  #pragma unroll
  for (int mi = 0; mi < 4; ++mi) {
    const int mbase = wm + mi * 16 + quad * 4;
    #pragma unroll
    for (int reg = 0; reg < 4; ++reg) {
      float x2r = x2g[bRow0 + mbase + reg];
      float ps = 0.0f;
      #pragma unroll
      for (int ni = 0; ni < 4; ++ni) {
        float cc = acc[mi][ni][reg];
        ps += __expf(__builtin_fmaf(-0.5f, x2r + s2v[ni], cc)) * wv[ni];
      }
      ps += __shfl_xor(ps, 1);
      ps += __shfl_xor(ps, 2);
      ps += __shfl_xor(ps, 4);
      ps += __shfl_xor(ps, 8);
      if (l16 == 0) atomicAdd(&accOut[bRow0 + mbase + reg], ps);
    }
  }
}

// ============================================================

__global__ __launch_bounds__(256) void svm_finalize(
    const float* __restrict__ ws, const float* __restrict__ bias,
    float* __restrict__ out) {
  int i = blockIdx.x * 256 + threadIdx.x;
  if (i < BQ) out[i] = tanhf(ws[i] + bias[0]);  // acc at offset 0 in all layouts
}

extern "C" void kernel_launch(void* const* d_in, const int* in_sizes, int n_in,
                              void* d_out, int out_size, void* d_ws, size_t ws_size,
                              hipStream_t stream) {
  const float* x       = (const float*)d_in[0];  // [2048, 256]
  const float* s       = (const float*)d_in[1];  // [50000, 256]
  const float* labels  = (const float*)d_in[2];  // [50000]
  const float* lambdas = (const float*)d_in[3];  // [50000]
  const float* bias    = (const float*)d_in[4];  // [1]
  float* out = (float*)d_out;                    // [2048]
  float* ws  = (float*)d_ws;

  if (ws_size >= WS_TOTAL_BYTES) {
    // precvt9 zeroes the accumulator region itself (blocks 0..7)
    svm_precvt9<<<(NPAD + BQ + 3) / 4, 256, 0, stream>>>(x, s, labels, lambdas, ws);
    svm_main13<<<16 * NG, 256, 0, stream>>>(ws);
  } else {
    hipMemsetAsync(ws, 0, BQ * sizeof(float), stream);
    svm_precompute<<<(NPTS + BQ + 3) / 4, 256, 0, stream>>>(x, s, labels, lambdas, ws);
    dim3 grid(391, BQ / 128);
    svm_main<<<grid, 256, 0, stream>>>(x, s, ws);
  }
  svm_finalize<<<BQ / 256, 256, 0, stream>>>(ws, bias, out);
}

// Round 5
// 155.732 us; speedup vs baseline: 1.0935x; 1.0935x over previous
//
#include <hip/hip_runtime.h>
#include <hip/hip_bf16.h>
#include <math.h>

// Problem constants (fixed by the reference)
#define NPTS 50000   // N data points
#define DIM  256     // feature dim (K of the GEMM)
#define BQ   2048    // batch of queries (M of the GEMM)
#define NPAD 50048   // N padded to multiple of 128

#define BK   32
#define CH   32      // n-rows per LDS chunk (16 KB)
#define NCH32 1564   // NPAD/CH
#define NG   64      // n-groups; grid = 8 m-tiles x 64 = 512 = 2 blocks/CU
                     // (register-limited). 64%8==0 -> b%8 = g%8: all 8
                     // m-tiles of a group land on one XCD (L2 reuse, 3.1 MB).
#define LOG2E 1.4426950408889634f

// ---------- fast-path ws layout (float offsets) ----------
//  acc   [0,      2048)
//  x2h   [2048,   4096)   0.5*log2e*||x||^2
//  t     [4096,  54144)   0.5*log2e*||s||^2 - log2|w|  (+inf when w==0)
//  sgn   [54144, 104192)  label sign
//  xb    [104192, 366336)   bf16 x
//  sb    [366336, 6772480)  bf16 s (NPAD rows, 0-padded)
#define WS_ACC 0
#define WS_X2  2048
#define WS_T   4096
#define WS_SGN 54144
#define WS_XB  104192
#define WS_SB  366336
#define WS_TOTAL_BYTES (6772480ull * 4ull)  // 27,089,920 B

// ---------- v1 fallback ws layout ----------
#define V1_ACC 0
#define V1_X2  2048
#define V1_S2  4096
#define V1_W   54096

typedef __bf16 bf16x8 __attribute__((ext_vector_type(8)));
typedef __bf16 bf16x4 __attribute__((ext_vector_type(4)));
typedef float  f32x4  __attribute__((ext_vector_type(4)));
typedef unsigned int u32;

__device__ __forceinline__ float fast_exp2(float v) {
#if __has_builtin(__builtin_amdgcn_exp2f)
  return __builtin_amdgcn_exp2f(v);   // raw v_exp_f32
#else
  return exp2f(v);
#endif
}

__device__ __forceinline__ void async_copy16(const __bf16* g, __bf16* l) {
  __builtin_amdgcn_global_load_lds(
      (const __attribute__((address_space(1))) u32*)g,
      (__attribute__((address_space(3))) u32*)l, 16, 0, 0);
}

// ============================================================
// FAST PATH (bf16, verified line)
// ============================================================

// One wave per row: fp32->bf16 convert into ws, plus folded epilogue
// constants t = s2h - log2|w| and sign. Blocks 0..7 zero the accumulator.
__global__ __launch_bounds__(256) void svm_precvt9(
    const float* __restrict__ x, const float* __restrict__ s,
    const float* __restrict__ labels, const float* __restrict__ lambdas,
    float* __restrict__ ws) {
  const int wid  = blockIdx.x * 4 + (threadIdx.x >> 6);
  const int lane = threadIdx.x & 63;
  __bf16* xb = (__bf16*)(ws + WS_XB);
  __bf16* sb = (__bf16*)(ws + WS_SB);

  if (blockIdx.x < 8) ws[WS_ACC + blockIdx.x * 256 + threadIdx.x] = 0.0f;

  if (wid < NPAD) {
    float4 v = make_float4(0.f, 0.f, 0.f, 0.f);
    if (wid < NPTS)
      v = reinterpret_cast<const float4*>(s + (size_t)wid * DIM)[lane];
    bf16x4 h = { (__bf16)v.x, (__bf16)v.y, (__bf16)v.z, (__bf16)v.w };
    *reinterpret_cast<bf16x4*>(sb + (size_t)wid * DIM + lane * 4) = h;
    float ss = v.x * v.x + v.y * v.y + v.z * v.z + v.w * v.w;
    #pragma unroll
    for (int off = 32; off > 0; off >>= 1) ss += __shfl_xor(ss, off);
    if (lane == 0) {
      float s2h = 0.5f * LOG2E * ss;
      float lam = (wid < NPTS) ? lambdas[wid] : 0.0f;
      float lab = (wid < NPTS) ? labels[wid] : 1.0f;
      float mag = lam > 0.0f ? lam : 0.0f;
      ws[WS_T + wid]   = (mag > 0.0f) ? s2h - log2f(mag) : __builtin_inff();
      ws[WS_SGN + wid] = lab;
    }
  } else if (wid < NPAD + BQ) {
    int r = wid - NPAD;
    float4 v = reinterpret_cast<const float4*>(x + (size_t)r * DIM)[lane];
    bf16x4 h = { (__bf16)v.x, (__bf16)v.y, (__bf16)v.z, (__bf16)v.w };
    *reinterpret_cast<bf16x4*>(xb + (size_t)r * DIM + lane * 4) = h;
    float ss = v.x * v.x + v.y * v.y + v.z * v.z + v.w * v.w;
    #pragma unroll
    for (int off = 32; off > 0; off >>= 1) ss += __shfl_xor(ss, off);
    if (lane == 0) ws[WS_X2 + r] = 0.5f * LOG2E * ss;
  }
}

// main14: attack the irreducible pipe. LDS B-traffic per FLOP scales 1/mi;
// mi=2 made the kernel LDS-bound (128 KB reads per 4.2 MFLOP block-chunk,
// floor 31 us, measured 65.7). mi=4 halves that and flips the bound to the
// MFMA pipe (floor 25 us). Register fit (pool=512/SIMD, (256,2) cap=256):
// afr 128 + acc[4][2] 32 + runAcc 16 + bfv 8 + tt/sg 4 + addr ~25 = ~215
// (round 1's mi=4 failed at ~252 because ni=4 made acc 64). CH=32 (ni=2)
// is what buys the acc halving. m-tile 256 = 4 waves x 64 rows; grid
// 8 x NG64 = 512 = 2 blocks/CU. Same verified swizzle/barrier structure.
__global__ __launch_bounds__(256, 2) void svm_main14(float* __restrict__ ws) {
  // [kt][n=32][32k] with 16B slot swizzle: slot(n,c) = c ^ ((n>>1)&3)
  __shared__ __bf16 sB[8 * CH * 32];  // 16 KB

  const __bf16* xb = (const __bf16*)(ws + WS_XB);
  const __bf16* sb = (const __bf16*)(ws + WS_SB);
  const float* x2g = ws + WS_X2;
  const float* tg  = ws + WS_T;
  const float* sgg = ws + WS_SGN;
  float* accOut    = ws + WS_ACC;

  const int t    = threadIdx.x;
  const int wave = t >> 6;            // 0..3
  const int lane = t & 63;
  const int quad = lane >> 4;
  const int l16  = lane & 15;
  const int g    = blockIdx.x & (NG - 1);  // n-group 0..63 (pow2: exact)
  const int mt   = blockIdx.x >> 6;        // m-tile 0..7 (256 rows each)
  const int m0   = mt * 256;
  const int c0   = (NCH32 * g) / NG;
  const int c1   = (NCH32 * (g + 1)) / NG;

  // A fragments: 4 mi x 8 kt x 16 B = 128 VGPR, loaded once, pinned opaque.
  f32x4 afr[4][8];
  #pragma unroll
  for (int mi = 0; mi < 4; ++mi)
    #pragma unroll
    for (int kt = 0; kt < 8; ++kt)
      afr[mi][kt] = *reinterpret_cast<const f32x4*>(
          xb + (size_t)(m0 + wave * 64 + mi * 16 + l16) * DIM + kt * BK + quad * 8);
  #pragma unroll
  for (int mi = 0; mi < 4; ++mi)
    #pragma unroll
    for (int kt = 0; kt < 8; ++kt)
      asm volatile("" : "+v"(afr[mi][kt]));  // no remat, stays in VGPRs

  float runAcc[4][4] = {{0.f, 0.f, 0.f, 0.f}, {0.f, 0.f, 0.f, 0.f},
                        {0.f, 0.f, 0.f, 0.f}, {0.f, 0.f, 0.f, 0.f}};

  // staging source swizzle (lane-only): slot fetched = (l&3) ^ ((l>>3)&3)
  const int srcswz = ((lane & 3) ^ ((lane >> 3) & 3)) * 8;  // bf16 elems
  // read-side swizzled 16B slot for this lane's B fragment
  const int rdswz = (quad ^ ((l16 >> 1) & 3)) * 8;          // bf16 elems

  for (int c = c0; c < c1; ++c) {
    __syncthreads();  // prior chunk's LDS reads done

    // Stage 32-n chunk [kt][n][32k], swizzled. 4 instrs/wave, 1 KB each.
    #pragma unroll
    for (int i = 0; i < 4; ++i) {
      int chn = wave * 4 + i;           // 0..15
      int kt = chn >> 1;                // 0..7
      int nb = (chn & 1) * 16;          // 0,16
      const __bf16* src = sb + (size_t)(c * CH + nb + (lane >> 2)) * DIM
                             + kt * BK + srcswz;
      async_copy16(src, &sB[kt * (CH * 32) + nb * 32] + lane * 8);
    }
    __syncthreads();  // vmcnt drain

    // Epilogue constants issued before MFMA so their latency hides under it.
    float tt[2], sg[2];
    #pragma unroll
    for (int ni = 0; ni < 2; ++ni) {
      int n = c * CH + ni * 16 + l16;
      tt[ni] = tg[n];
      sg[ni] = sgg[n];
    }

    f32x4 acc[4][2];
    #pragma unroll
    for (int mi = 0; mi < 4; ++mi)
      #pragma unroll
      for (int ni = 0; ni < 2; ++ni)
        acc[mi][ni] = (f32x4)(0.0f);

    #pragma unroll
    for (int kt = 0; kt < 8; ++kt) {
      bf16x8 bfv[2];
      #pragma unroll
      for (int ni = 0; ni < 2; ++ni)
        bfv[ni] = *reinterpret_cast<const bf16x8*>(
            &sB[kt * (CH * 32) + (ni * 16 + l16) * 32 + rdswz]);
      #pragma unroll
      for (int mi = 0; mi < 4; ++mi)
        #pragma unroll
        for (int ni = 0; ni < 2; ++ni)
          acc[mi][ni] = __builtin_amdgcn_mfma_f32_16x16x32_bf16(
              __builtin_bit_cast(bf16x8, afr[mi][kt]), bfv[ni],
              acc[mi][ni], 0, 0, 0);
    }

    // Hoisted epilogue: p += sgn * exp2(dot*log2e - t_n); x2 applied at end.
    #pragma unroll
    for (int mi = 0; mi < 4; ++mi)
      #pragma unroll
      for (int reg = 0; reg < 4; ++reg) {
        float p = runAcc[mi][reg];
        #pragma unroll
        for (int ni = 0; ni < 2; ++ni)
          p = __builtin_fmaf(sg[ni],
                fast_exp2(__builtin_fmaf(acc[mi][ni][reg], LOG2E, -tt[ni])), p);
        runAcc[mi][reg] = p;
      }
  }

  // reduce over the 16 n-column lanes; scale by exp2(-x2h); one atomic/row.
  #pragma unroll
  for (int mi = 0; mi < 4; ++mi)
    #pragma unroll
    for (int reg = 0; reg < 4; ++reg) {
      float v = runAcc[mi][reg];
      v += __shfl_xor(v, 1);
      v += __shfl_xor(v, 2);
      v += __shfl_xor(v, 4);
      v += __shfl_xor(v, 8);
      if (l16 == 0) {
        int row = m0 + wave * 64 + mi * 16 + quad * 4 + reg;
        atomicAdd(&accOut[row], fast_exp2(-x2g[row]) * v);
      }
    }
}

// ============================================================
// V1 FALLBACK (used only if ws_size too small)
// ============================================================

__global__ __launch_bounds__(256) void svm_precompute(
    const float* __restrict__ x, const float* __restrict__ s,
    const float* __restrict__ labels, const float* __restrict__ lambdas,
    float* __restrict__ ws) {
  int wid  = blockIdx.x * 4 + (threadIdx.x >> 6);
  int lane = threadIdx.x & 63;
  const float* src;
  if (wid < NPTS)           src = s + (size_t)wid * DIM;
  else if (wid < NPTS + BQ) src = x + (size_t)(wid - NPTS) * DIM;
  else return;
  float4 v = reinterpret_cast<const float4*>(src)[lane];
  float ss = v.x * v.x + v.y * v.y + v.z * v.z + v.w * v.w;
  #pragma unroll
  for (int off = 32; off > 0; off >>= 1) ss += __shfl_xor(ss, off);
  if (lane == 0) {
    if (wid < NPTS) {
      ws[V1_S2 + wid] = ss;
      float lam = lambdas[wid];
      ws[V1_W + wid] = labels[wid] * (lam > 0.0f ? lam : 0.0f);
    } else {
      ws[V1_X2 + (wid - NPTS)] = ss;
    }
  }
}

__global__ __launch_bounds__(256) void svm_main(
    const float* __restrict__ x, const float* __restrict__ s,
    const float* __restrict__ ws) {
  __shared__ __bf16 sA[128 * BK];
  __shared__ __bf16 sB2[128 * BK];

  const int t    = threadIdx.x;
  const int wave = t >> 6;
  const int lane = t & 63;
  const int quad = lane >> 4;
  const int l16  = lane & 15;
  const int wm   = (wave & 1) * 64;
  const int wn   = (wave >> 1) * 64;
  const int bRow0 = blockIdx.y * 128;
  const int n0    = blockIdx.x * 128;

  f32x4 acc[4][4];
  #pragma unroll
  for (int i = 0; i < 4; ++i)
    #pragma unroll
    for (int j = 0; j < 4; ++j)
      acc[i][j] = (f32x4)(0.0f);

  for (int kt = 0; kt < DIM / BK; ++kt) {
    const int k0 = kt * BK;
    __syncthreads();
    #pragma unroll
    for (int i = 0; i < 4; ++i) {
      int slot = t + i * 256;
      int r  = slot >> 3;
      int c4 = slot & 7;
      float4 va = reinterpret_cast<const float4*>(
          x + (size_t)(bRow0 + r) * DIM + k0)[c4];
      bf16x4 ha = { (__bf16)va.x, (__bf16)va.y, (__bf16)va.z, (__bf16)va.w };
      *reinterpret_cast<bf16x4*>(&sA[r * BK + c4 * 4]) = ha;

      int nrow = n0 + r;
      float4 vb = make_float4(0.f, 0.f, 0.f, 0.f);
      if (nrow < NPTS)
        vb = reinterpret_cast<const float4*>(
            s + (size_t)nrow * DIM + k0)[c4];
      bf16x4 hb = { (__bf16)vb.x, (__bf16)vb.y, (__bf16)vb.z, (__bf16)vb.w };
      *reinterpret_cast<bf16x4*>(&sB2[r * BK + c4 * 4]) = hb;
    }
    __syncthreads();

    bf16x8 af[4], bfv[4];
    #pragma unroll
    for (int mi = 0; mi < 4; ++mi)
      af[mi] = *reinterpret_cast<const bf16x8*>(
          &sA[(wm + mi * 16 + l16) * BK + quad * 8]);
    #pragma unroll
    for (int ni = 0; ni < 4; ++ni)
      bfv[ni] = *reinterpret_cast<const bf16x8*>(
          &sB2[(wn + ni * 16 + l16) * BK + quad * 8]);
    #pragma unroll
    for (int mi = 0; mi < 4; ++mi)
      #pragma unroll
      for (int ni = 0; ni < 4; ++ni)
        acc[mi][ni] = __builtin_amdgcn_mfma_f32_16x16x32_bf16(
            af[mi], bfv[ni], acc[mi][ni], 0, 0, 0);
  }

  const float* x2g = ws + V1_X2;
  const float* s2g = ws + V1_S2;
  const float* wg  = ws + V1_W;
  float* accOut    = (float*)ws + V1_ACC;

  float s2v[4], wv[4];
  #pragma unroll
  for (int ni = 0; ni < 4; ++ni) {
    int n = n0 + wn + ni * 16 + l16;
    bool ok = n < NPTS;
    s2v[ni] = ok ? s2g[n] : 0.0f;
    wv[ni]  = ok ? wg[n]  : 0.0f;
  }
  #pragma unroll
  for (int mi = 0; mi < 4; ++mi) {
    const int mbase = wm + mi * 16 + quad * 4;
    #pragma unroll
    for (int reg = 0; reg < 4; ++reg) {
      float x2r = x2g[bRow0 + mbase + reg];
      float ps = 0.0f;
      #pragma unroll
      for (int ni = 0; ni < 4; ++ni) {
        float cc = acc[mi][ni][reg];
        ps += __expf(__builtin_fmaf(-0.5f, x2r + s2v[ni], cc)) * wv[ni];
      }
      ps += __shfl_xor(ps, 1);
      ps += __shfl_xor(ps, 2);
      ps += __shfl_xor(ps, 4);
      ps += __shfl_xor(ps, 8);
      if (l16 == 0) atomicAdd(&accOut[bRow0 + mbase + reg], ps);
    }
  }
}

// ============================================================

__global__ __launch_bounds__(256) void svm_finalize(
    const float* __restrict__ ws, const float* __restrict__ bias,
    float* __restrict__ out) {
  int i = blockIdx.x * 256 + threadIdx.x;
  if (i < BQ) out[i] = tanhf(ws[i] + bias[0]);  // acc at offset 0 in all layouts
}

extern "C" void kernel_launch(void* const* d_in, const int* in_sizes, int n_in,
                              void* d_out, int out_size, void* d_ws, size_t ws_size,
                              hipStream_t stream) {
  const float* x       = (const float*)d_in[0];  // [2048, 256]
  const float* s       = (const float*)d_in[1];  // [50000, 256]
  const float* labels  = (const float*)d_in[2];  // [50000]
  const float* lambdas = (const float*)d_in[3];  // [50000]
  const float* bias    = (const float*)d_in[4];  // [1]
  float* out = (float*)d_out;                    // [2048]
  float* ws  = (float*)d_ws;

  if (ws_size >= WS_TOTAL_BYTES) {
    // precvt9 zeroes the accumulator region itself (blocks 0..7)
    svm_precvt9<<<(NPAD + BQ + 3) / 4, 256, 0, stream>>>(x, s, labels, lambdas, ws);
    svm_main14<<<8 * NG, 256, 0, stream>>>(ws);
  } else {
    hipMemsetAsync(ws, 0, BQ * sizeof(float), stream);
    svm_precompute<<<(NPTS + BQ + 3) / 4, 256, 0, stream>>>(x, s, labels, lambdas, ws);
    dim3 grid(391, BQ / 128);
    svm_main<<<grid, 256, 0, stream>>>(x, s, ws);
  }
  svm_finalize<<<BQ / 256, 256, 0, stream>>>(ws, bias, out);
}

// Round 6
// 152.480 us; speedup vs baseline: 1.1169x; 1.0213x over previous
//
#include <hip/hip_runtime.h>
#include <hip/hip_bf16.h>
#include <math.h>

// Problem constants (fixed by the reference)
#define NPTS 50000   // N data points
#define DIM  256     // feature dim (K of the GEMM)
#define BQ   2048    // batch of queries (M of the GEMM)
#define NPAD 50048   // N padded to multiple of 128

#define BK   32
#define CH   32      // n-rows per LDS chunk (16 KB per buffer)
#define NCH32 1564   // NPAD/CH
#define NG   64      // n-groups; grid = 8 m-tiles x 64 = 512 = 2 blocks/CU
                     // (register-limited). 64%8==0 -> b%8 = g%8: all 8
                     // m-tiles of a group land on one XCD (L2 reuse, 3.1 MB).
#define LOG2E 1.4426950408889634f

// ---------- fast-path ws layout (float offsets) ----------
//  acc   [0,      2048)
//  x2h   [2048,   4096)   0.5*log2e*||x||^2
//  t     [4096,  54144)   0.5*log2e*||s||^2 - log2|w|  (+inf when w==0)
//  sgn   [54144, 104192)  label sign
//  xb    [104192, 366336)   bf16 x
//  sb    [366336, 6772480)  bf16 s (NPAD rows, 0-padded)
#define WS_ACC 0
#define WS_X2  2048
#define WS_T   4096
#define WS_SGN 54144
#define WS_XB  104192
#define WS_SB  366336
#define WS_TOTAL_BYTES (6772480ull * 4ull)  // 27,089,920 B

// ---------- v1 fallback ws layout ----------
#define V1_ACC 0
#define V1_X2  2048
#define V1_S2  4096
#define V1_W   54096

typedef __bf16 bf16x8 __attribute__((ext_vector_type(8)));
typedef __bf16 bf16x4 __attribute__((ext_vector_type(4)));
typedef float  f32x4  __attribute__((ext_vector_type(4)));
typedef unsigned int u32;

__device__ __forceinline__ float fast_exp2(float v) {
#if __has_builtin(__builtin_amdgcn_exp2f)
  return __builtin_amdgcn_exp2f(v);   // raw v_exp_f32
#else
  return exp2f(v);
#endif
}

__device__ __forceinline__ void async_copy16(const __bf16* g, __bf16* l) {
  __builtin_amdgcn_global_load_lds(
      (const __attribute__((address_space(1))) u32*)g,
      (__attribute__((address_space(3))) u32*)l, 16, 0, 0);
}

// ============================================================
// FAST PATH (bf16, verified line)
// ============================================================

// One wave per row: fp32->bf16 convert into ws, plus folded epilogue
// constants t = s2h - log2|w| and sign. Blocks 0..7 zero the accumulator.
__global__ __launch_bounds__(256) void svm_precvt9(
    const float* __restrict__ x, const float* __restrict__ s,
    const float* __restrict__ labels, const float* __restrict__ lambdas,
    float* __restrict__ ws) {
  const int wid  = blockIdx.x * 4 + (threadIdx.x >> 6);
  const int lane = threadIdx.x & 63;
  __bf16* xb = (__bf16*)(ws + WS_XB);
  __bf16* sb = (__bf16*)(ws + WS_SB);

  if (blockIdx.x < 8) ws[WS_ACC + blockIdx.x * 256 + threadIdx.x] = 0.0f;

  if (wid < NPAD) {
    float4 v = make_float4(0.f, 0.f, 0.f, 0.f);
    if (wid < NPTS)
      v = reinterpret_cast<const float4*>(s + (size_t)wid * DIM)[lane];
    bf16x4 h = { (__bf16)v.x, (__bf16)v.y, (__bf16)v.z, (__bf16)v.w };
    *reinterpret_cast<bf16x4*>(sb + (size_t)wid * DIM + lane * 4) = h;
    float ss = v.x * v.x + v.y * v.y + v.z * v.z + v.w * v.w;
    #pragma unroll
    for (int off = 32; off > 0; off >>= 1) ss += __shfl_xor(ss, off);
    if (lane == 0) {
      float s2h = 0.5f * LOG2E * ss;
      float lam = (wid < NPTS) ? lambdas[wid] : 0.0f;
      float lab = (wid < NPTS) ? labels[wid] : 1.0f;
      float mag = lam > 0.0f ? lam : 0.0f;
      ws[WS_T + wid]   = (mag > 0.0f) ? s2h - log2f(mag) : __builtin_inff();
      ws[WS_SGN + wid] = lab;
    }
  } else if (wid < NPAD + BQ) {
    int r = wid - NPAD;
    float4 v = reinterpret_cast<const float4*>(x + (size_t)r * DIM)[lane];
    bf16x4 h = { (__bf16)v.x, (__bf16)v.y, (__bf16)v.z, (__bf16)v.w };
    *reinterpret_cast<bf16x4*>(xb + (size_t)r * DIM + lane * 4) = h;
    float ss = v.x * v.x + v.y * v.y + v.z * v.z + v.w * v.w;
    #pragma unroll
    for (int off = 32; off > 0; off >>= 1) ss += __shfl_xor(ss, off);
    if (lane == 0) ws[WS_X2 + r] = 0.5f * LOG2E * ss;
  }
}

// main15 = main14 (mi=4/ni=2, MFMA-bound inner loop: 1240 cyc MFMA vs 768
// cyc LDS per chunk, regs ~215 < 256 cap) + double-buffered 2x16 KB LDS
// with prefetch-before-compute, ONE barrier per chunk. Why dbuf works NOW:
// occupancy is register-limited at 2 blocks/CU, so the extra 16 KB LDS is
// free (round-3's dbuf lost a block to 64 KB LDS); and the 1240-cyc MFMA
// phase exceeds worst-case LLC fetch latency (~900 cyc), so the prefetch
// fully lands before the end-of-iteration barrier's vmcnt(0) drain.
// tt/sg are issued BEFORE the STAGE so their wait leaves prefetch in flight.
__global__ __launch_bounds__(256, 2) void svm_main15(float* __restrict__ ws) {
  // [buf][kt][n=32][32k] with 16B slot swizzle: slot(n,c) = c ^ ((n>>1)&3)
  __shared__ __bf16 sB[2][8 * CH * 32];  // 2 x 16 KB

  const __bf16* xb = (const __bf16*)(ws + WS_XB);
  const __bf16* sb = (const __bf16*)(ws + WS_SB);
  const float* x2g = ws + WS_X2;
  const float* tg  = ws + WS_T;
  const float* sgg = ws + WS_SGN;
  float* accOut    = ws + WS_ACC;

  const int t    = threadIdx.x;
  const int wave = t >> 6;            // 0..3
  const int lane = t & 63;
  const int quad = lane >> 4;
  const int l16  = lane & 15;
  const int g    = blockIdx.x & (NG - 1);  // n-group 0..63 (pow2: exact)
  const int mt   = blockIdx.x >> 6;        // m-tile 0..7 (256 rows each)
  const int m0   = mt * 256;
  const int c0   = (NCH32 * g) / NG;
  const int c1   = (NCH32 * (g + 1)) / NG;

  // staging source swizzle (lane-only): slot fetched = (l&3) ^ ((l>>3)&3)
  const int srcswz = ((lane & 3) ^ ((lane >> 3) & 3)) * 8;  // bf16 elems
  // read-side swizzled 16B slot for this lane's B fragment
  const int rdswz = (quad ^ ((l16 >> 1) & 3)) * 8;          // bf16 elems

#define STAGE15(buf, cc)                                                      \
  do {                                                                        \
    _Pragma("unroll")                                                         \
    for (int i = 0; i < 4; ++i) {                                             \
      int chn = wave * 4 + i;            /* 0..15 */                          \
      int kt = chn >> 1;                 /* 0..7  */                          \
      int nb = (chn & 1) * 16;           /* 0,16  */                          \
      const __bf16* src = sb + (size_t)((cc) * CH + nb + (lane >> 2)) * DIM   \
                             + kt * BK + srcswz;                              \
      async_copy16(src, &sB[(buf)][kt * (CH * 32) + nb * 32] + lane * 8);     \
    }                                                                         \
  } while (0)

  // Prologue: kick chunk c0 into buf 0; its fetch flies under the A-loads.
  STAGE15(0, c0);

  // A fragments: 4 mi x 8 kt x 16 B = 128 VGPR, loaded once, pinned opaque.
  f32x4 afr[4][8];
  #pragma unroll
  for (int mi = 0; mi < 4; ++mi)
    #pragma unroll
    for (int kt = 0; kt < 8; ++kt)
      afr[mi][kt] = *reinterpret_cast<const f32x4*>(
          xb + (size_t)(m0 + wave * 64 + mi * 16 + l16) * DIM + kt * BK + quad * 8);
  #pragma unroll
  for (int mi = 0; mi < 4; ++mi)
    #pragma unroll
    for (int kt = 0; kt < 8; ++kt)
      asm volatile("" : "+v"(afr[mi][kt]));  // no remat, stays in VGPRs

  float runAcc[4][4] = {{0.f, 0.f, 0.f, 0.f}, {0.f, 0.f, 0.f, 0.f},
                        {0.f, 0.f, 0.f, 0.f}, {0.f, 0.f, 0.f, 0.f}};

  __syncthreads();  // chunk c0 resident in sB[0]

  int cur = 0;
  for (int c = c0; c < c1; ++c) {
    // (1) Epilogue constants for THIS chunk (issued before STAGE: in-order
    //     vmcnt means their wait leaves the 4 prefetch loads in flight).
    float tt[2], sg[2];
    #pragma unroll
    for (int ni = 0; ni < 2; ++ni) {
      int n = c * CH + ni * 16 + l16;
      tt[ni] = tg[n];
      sg[ni] = sgg[n];
    }

    // (2) Prefetch next chunk into the other buffer; ~900-cyc fetch hides
    //     under the 1240-cyc MFMA phase below. Target buffer's last readers
    //     finished at the previous iteration's barrier.
    if (c + 1 < c1) STAGE15(cur ^ 1, c + 1);

    // (3) Compute current chunk (MFMA-bound: 64 MFMA/wave vs 16 ds_read).
    f32x4 acc[4][2];
    #pragma unroll
    for (int mi = 0; mi < 4; ++mi)
      #pragma unroll
      for (int ni = 0; ni < 2; ++ni)
        acc[mi][ni] = (f32x4)(0.0f);

    #pragma unroll
    for (int kt = 0; kt < 8; ++kt) {
      bf16x8 bfv[2];
      #pragma unroll
      for (int ni = 0; ni < 2; ++ni)
        bfv[ni] = *reinterpret_cast<const bf16x8*>(
            &sB[cur][kt * (CH * 32) + (ni * 16 + l16) * 32 + rdswz]);
      #pragma unroll
      for (int mi = 0; mi < 4; ++mi)
        #pragma unroll
        for (int ni = 0; ni < 2; ++ni)
          acc[mi][ni] = __builtin_amdgcn_mfma_f32_16x16x32_bf16(
              __builtin_bit_cast(bf16x8, afr[mi][kt]), bfv[ni],
              acc[mi][ni], 0, 0, 0);
    }

    // (4) Hoisted epilogue: p += sgn * exp2(dot*log2e - t_n).
    #pragma unroll
    for (int mi = 0; mi < 4; ++mi)
      #pragma unroll
      for (int reg = 0; reg < 4; ++reg) {
        float p = runAcc[mi][reg];
        #pragma unroll
        for (int ni = 0; ni < 2; ++ni)
          p = __builtin_fmaf(sg[ni],
                fast_exp2(__builtin_fmaf(acc[mi][ni][reg], LOG2E, -tt[ni])), p);
        runAcc[mi][reg] = p;
      }

    // (5) One barrier per chunk: drains vmcnt (prefetch has had the whole
    //     compute phase to land -> near-free) and syncs buffer reuse.
    __syncthreads();
    cur ^= 1;
  }

  // reduce over the 16 n-column lanes; scale by exp2(-x2h); one atomic/row.
  #pragma unroll
  for (int mi = 0; mi < 4; ++mi)
    #pragma unroll
    for (int reg = 0; reg < 4; ++reg) {
      float v = runAcc[mi][reg];
      v += __shfl_xor(v, 1);
      v += __shfl_xor(v, 2);
      v += __shfl_xor(v, 4);
      v += __shfl_xor(v, 8);
      if (l16 == 0) {
        int row = m0 + wave * 64 + mi * 16 + quad * 4 + reg;
        atomicAdd(&accOut[row], fast_exp2(-x2g[row]) * v);
      }
    }
#undef STAGE15
}

// ============================================================
// V1 FALLBACK (used only if ws_size too small)
// ============================================================

__global__ __launch_bounds__(256) void svm_precompute(
    const float* __restrict__ x, const float* __restrict__ s,
    const float* __restrict__ labels, const float* __restrict__ lambdas,
    float* __restrict__ ws) {
  int wid  = blockIdx.x * 4 + (threadIdx.x >> 6);
  int lane = threadIdx.x & 63;
  const float* src;
  if (wid < NPTS)           src = s + (size_t)wid * DIM;
  else if (wid < NPTS + BQ) src = x + (size_t)(wid - NPTS) * DIM;
  else return;
  float4 v = reinterpret_cast<const float4*>(src)[lane];
  float ss = v.x * v.x + v.y * v.y + v.z * v.z + v.w * v.w;
  #pragma unroll
  for (int off = 32; off > 0; off >>= 1) ss += __shfl_xor(ss, off);
  if (lane == 0) {
    if (wid < NPTS) {
      ws[V1_S2 + wid] = ss;
      float lam = lambdas[wid];
      ws[V1_W + wid] = labels[wid] * (lam > 0.0f ? lam : 0.0f);
    } else {
      ws[V1_X2 + (wid - NPTS)] = ss;
    }
  }
}

__global__ __launch_bounds__(256) void svm_main(
    const float* __restrict__ x, const float* __restrict__ s,
    const float* __restrict__ ws) {
  __shared__ __bf16 sA[128 * BK];
  __shared__ __bf16 sB2[128 * BK];

  const int t    = threadIdx.x;
  const int wave = t >> 6;
  const int lane = t & 63;
  const int quad = lane >> 4;
  const int l16  = lane & 15;
  const int wm   = (wave & 1) * 64;
  const int wn   = (wave >> 1) * 64;
  const int bRow0 = blockIdx.y * 128;
  const int n0    = blockIdx.x * 128;

  f32x4 acc[4][4];
  #pragma unroll
  for (int i = 0; i < 4; ++i)
    #pragma unroll
    for (int j = 0; j < 4; ++j)
      acc[i][j] = (f32x4)(0.0f);

  for (int kt = 0; kt < DIM / BK; ++kt) {
    const int k0 = kt * BK;
    __syncthreads();
    #pragma unroll
    for (int i = 0; i < 4; ++i) {
      int slot = t + i * 256;
      int r  = slot >> 3;
      int c4 = slot & 7;
      float4 va = reinterpret_cast<const float4*>(
          x + (size_t)(bRow0 + r) * DIM + k0)[c4];
      bf16x4 ha = { (__bf16)va.x, (__bf16)va.y, (__bf16)va.z, (__bf16)va.w };
      *reinterpret_cast<bf16x4*>(&sA[r * BK + c4 * 4]) = ha;

      int nrow = n0 + r;
      float4 vb = make_float4(0.f, 0.f, 0.f, 0.f);
      if (nrow < NPTS)
        vb = reinterpret_cast<const float4*>(
            s + (size_t)nrow * DIM + k0)[c4];
      bf16x4 hb = { (__bf16)vb.x, (__bf16)vb.y, (__bf16)vb.z, (__bf16)vb.w };
      *reinterpret_cast<bf16x4*>(&sB2[r * BK + c4 * 4]) = hb;
    }
    __syncthreads();

    bf16x8 af[4], bfv[4];
    #pragma unroll
    for (int mi = 0; mi < 4; ++mi)
      af[mi] = *reinterpret_cast<const bf16x8*>(
          &sA[(wm + mi * 16 + l16) * BK + quad * 8]);
    #pragma unroll
    for (int ni = 0; ni < 4; ++ni)
      bfv[ni] = *reinterpret_cast<const bf16x8*>(
          &sB2[(wn + ni * 16 + l16) * BK + quad * 8]);
    #pragma unroll
    for (int mi = 0; mi < 4; ++mi)
      #pragma unroll
      for (int ni = 0; ni < 4; ++ni)
        acc[mi][ni] = __builtin_amdgcn_mfma_f32_16x16x32_bf16(
            af[mi], bfv[ni], acc[mi][ni], 0, 0, 0);
  }

  const float* x2g = ws + V1_X2;
  const float* s2g = ws + V1_S2;
  const float* wg  = ws + V1_W;
  float* accOut    = (float*)ws + V1_ACC;

  float s2v[4], wv[4];
  #pragma unroll
  for (int ni = 0; ni < 4; ++ni) {
    int n = n0 + wn + ni * 16 + l16;
    bool ok = n < NPTS;
    s2v[ni] = ok ? s2g[n] : 0.0f;
    wv[ni]  = ok ? wg[n]  : 0.0f;
  }
  #pragma unroll
  for (int mi = 0; mi < 4; ++mi) {
    const int mbase = wm + mi * 16 + quad * 4;
    #pragma unroll
    for (int reg = 0; reg < 4; ++reg) {
      float x2r = x2g[bRow0 + mbase + reg];
      float ps = 0.0f;
      #pragma unroll
      for (int ni = 0; ni < 4; ++ni) {
        float cc = acc[mi][ni][reg];
        ps += __expf(__builtin_fmaf(-0.5f, x2r + s2v[ni], cc)) * wv[ni];
      }
      ps += __shfl_xor(ps, 1);
      ps += __shfl_xor(ps, 2);
      ps += __shfl_xor(ps, 4);
      ps += __shfl_xor(ps, 8);
      if (l16 == 0) atomicAdd(&accOut[bRow0 + mbase + reg], ps);
    }
  }
}

// ============================================================

__global__ __launch_bounds__(256) void svm_finalize(
    const float* __restrict__ ws, const float* __restrict__ bias,
    float* __restrict__ out) {
  int i = blockIdx.x * 256 + threadIdx.x;
  if (i < BQ) out[i] = tanhf(ws[i] + bias[0]);  // acc at offset 0 in all layouts
}

extern "C" void kernel_launch(void* const* d_in, const int* in_sizes, int n_in,
                              void* d_out, int out_size, void* d_ws, size_t ws_size,
                              hipStream_t stream) {
  const float* x       = (const float*)d_in[0];  // [2048, 256]
  const float* s       = (const float*)d_in[1];  // [50000, 256]
  const float* labels  = (const float*)d_in[2];  // [50000]
  const float* lambdas = (const float*)d_in[3];  // [50000]
  const float* bias    = (const float*)d_in[4];  // [1]
  float* out = (float*)d_out;                    // [2048]
  float* ws  = (float*)d_ws;

  if (ws_size >= WS_TOTAL_BYTES) {
    // precvt9 zeroes the accumulator region itself (blocks 0..7)
    svm_precvt9<<<(NPAD + BQ + 3) / 4, 256, 0, stream>>>(x, s, labels, lambdas, ws);
    svm_main15<<<8 * NG, 256, 0, stream>>>(ws);
  } else {
    hipMemsetAsync(ws, 0, BQ * sizeof(float), stream);
    svm_precompute<<<(NPTS + BQ + 3) / 4, 256, 0, stream>>>(x, s, labels, lambdas, ws);
    dim3 grid(391, BQ / 128);
    svm_main<<<grid, 256, 0, stream>>>(x, s, ws);
  }
  svm_finalize<<<BQ / 256, 256, 0, stream>>>(ws, bias, out);
}